// Round 1
// baseline (3965.173 us; speedup 1.0000x reference)
//
#include <hip/hip_runtime.h>
#include <hip/hip_bf16.h>

#define NTOK   2048     // B*S
#define DIM    768      // D
#define NEXP   8        // E
#define NLAYER 4        // L
#define FDIM   3072     // F = 4*D
#define TOPK   2

// ---------------------------------------------------------------------------
// Plain GEMM: C[M,N] = A[M,Kd] @ B[Kd,N] + bias[N]
// 128x128 tile, TK=16, 256 threads, 8x8 micro-tile per thread.
// M, N assumed multiples of 128; Kd multiple of 16 (true for all our shapes).
// ---------------------------------------------------------------------------
__global__ __launch_bounds__(256) void gemm_f32(
    const float* __restrict__ A, const float* __restrict__ Bm,
    const float* __restrict__ bias, float* __restrict__ C,
    int M, int Kd, int N)
{
    const int tid = threadIdx.x;
    const int n0 = blockIdx.x * 128;
    const int m0 = blockIdx.y * 128;
    __shared__ __align__(16) float As[16][128];
    __shared__ __align__(16) float Bs[16][128];
    float acc[8][8];
#pragma unroll
    for (int i = 0; i < 8; ++i)
#pragma unroll
        for (int j = 0; j < 8; ++j) acc[i][j] = 0.f;

    const int tx = tid & 15, ty = tid >> 4;
    const int mA = tid >> 2, kvA = tid & 3;   // A: row mA(+64), float4 slot kvA
    const int kB = tid >> 5, nvB = tid & 31;  // B: row kB(+8), float4 slot nvB

    for (int k0 = 0; k0 < Kd; k0 += 16) {
#pragma unroll
        for (int i = 0; i < 2; ++i) {
            int m = mA + i * 64;
            float4 av = *(const float4*)&A[(size_t)(m0 + m) * Kd + k0 + kvA * 4];
            As[kvA * 4 + 0][m] = av.x;
            As[kvA * 4 + 1][m] = av.y;
            As[kvA * 4 + 2][m] = av.z;
            As[kvA * 4 + 3][m] = av.w;
        }
#pragma unroll
        for (int i = 0; i < 2; ++i) {
            int k = kB + i * 8;
            *(float4*)&Bs[k][nvB * 4] =
                *(const float4*)&Bm[(size_t)(k0 + k) * N + n0 + nvB * 4];
        }
        __syncthreads();
#pragma unroll
        for (int kk = 0; kk < 16; ++kk) {
            float4 a0 = *(const float4*)&As[kk][ty * 8];
            float4 a1 = *(const float4*)&As[kk][ty * 8 + 4];
            float4 b0 = *(const float4*)&Bs[kk][tx * 8];
            float4 b1 = *(const float4*)&Bs[kk][tx * 8 + 4];
            float a[8] = {a0.x, a0.y, a0.z, a0.w, a1.x, a1.y, a1.z, a1.w};
            float b[8] = {b0.x, b0.y, b0.z, b0.w, b1.x, b1.y, b1.z, b1.w};
#pragma unroll
            for (int i = 0; i < 8; ++i)
#pragma unroll
                for (int j = 0; j < 8; ++j) acc[i][j] += a[i] * b[j];
        }
        __syncthreads();
    }
#pragma unroll
    for (int i = 0; i < 8; ++i) {
        int m = m0 + ty * 8 + i;
        float* crow = C + (size_t)m * N + n0;
#pragma unroll
        for (int j = 0; j < 8; ++j) {
            int n = tx * 8 + j;
            crow[n] = acc[i][j] + bias[n0 + n];
        }
    }
}

// ---------------------------------------------------------------------------
// Grouped (per-expert) GEMM with optional row gather and ragged row masking.
//   expert e = blockIdx.z; rows are [offsets[e], offsets[e]+counts[e]) of C.
//   A row for local row i: tok_list ? tok_list[e*NTOK+i] (gather from z)
//                                   : offsets[e]+i       (contiguous h1)
//   B = Wbase + e*strideW, bias = biasBase + e*strideBias.
// Grid sized for the worst case (all tokens on one expert); early-exit on
// device-side counts keeps it graph-capture-safe.
// ---------------------------------------------------------------------------
__global__ __launch_bounds__(256) void gemm_grouped(
    const float* __restrict__ Asrc, const float* __restrict__ Wbase,
    const float* __restrict__ biasBase, float* __restrict__ C,
    const int* __restrict__ counts, const int* __restrict__ offsets,
    const int* __restrict__ tok_list,
    int Kd, int N, size_t strideW, int strideBias, int relu)
{
    const int e = blockIdx.z;
    const int cnt = counts[e];
    const int rt = blockIdx.y;
    if (rt * 128 >= cnt) return;
    const int off = offsets[e];
    const float* Bm = Wbase + (size_t)e * strideW;
    const float* bias = biasBase + (size_t)e * strideBias;

    const int tid = threadIdx.x;
    const int n0 = blockIdx.x * 128;
    __shared__ __align__(16) float As[16][128];
    __shared__ __align__(16) float Bs[16][128];
    float acc[8][8];
#pragma unroll
    for (int i = 0; i < 8; ++i)
#pragma unroll
        for (int j = 0; j < 8; ++j) acc[i][j] = 0.f;

    const int tx = tid & 15, ty = tid >> 4;
    const int mA = tid >> 2, kvA = tid & 3;
    const int kB = tid >> 5, nvB = tid & 31;

    // Resolve the two A-row pointers this thread loads (null => masked row).
    const float* arow[2];
#pragma unroll
    for (int i = 0; i < 2; ++i) {
        int gi = rt * 128 + mA + i * 64;
        if (gi < cnt) {
            int r = tok_list ? tok_list[e * NTOK + gi] : (off + gi);
            arow[i] = Asrc + (size_t)r * Kd;
        } else {
            arow[i] = nullptr;
        }
    }

    for (int k0 = 0; k0 < Kd; k0 += 16) {
#pragma unroll
        for (int i = 0; i < 2; ++i) {
            int m = mA + i * 64;
            float4 av = make_float4(0.f, 0.f, 0.f, 0.f);
            if (arow[i]) av = *(const float4*)&arow[i][k0 + kvA * 4];
            As[kvA * 4 + 0][m] = av.x;
            As[kvA * 4 + 1][m] = av.y;
            As[kvA * 4 + 2][m] = av.z;
            As[kvA * 4 + 3][m] = av.w;
        }
#pragma unroll
        for (int i = 0; i < 2; ++i) {
            int k = kB + i * 8;
            *(float4*)&Bs[k][nvB * 4] =
                *(const float4*)&Bm[(size_t)(k0 + k) * N + n0 + nvB * 4];
        }
        __syncthreads();
#pragma unroll
        for (int kk = 0; kk < 16; ++kk) {
            float4 a0 = *(const float4*)&As[kk][ty * 8];
            float4 a1 = *(const float4*)&As[kk][ty * 8 + 4];
            float4 b0 = *(const float4*)&Bs[kk][tx * 8];
            float4 b1 = *(const float4*)&Bs[kk][tx * 8 + 4];
            float a[8] = {a0.x, a0.y, a0.z, a0.w, a1.x, a1.y, a1.z, a1.w};
            float b[8] = {b0.x, b0.y, b0.z, b0.w, b1.x, b1.y, b1.z, b1.w};
#pragma unroll
            for (int i = 0; i < 8; ++i)
#pragma unroll
                for (int j = 0; j < 8; ++j) acc[i][j] += a[i] * b[j];
        }
        __syncthreads();
    }
#pragma unroll
    for (int i = 0; i < 8; ++i) {
        int gi = rt * 128 + ty * 8 + i;
        if (gi >= cnt) continue;
        float* crow = C + (size_t)(off + gi) * N + n0;
#pragma unroll
        for (int j = 0; j < 8; ++j) {
            float v = acc[i][j] + bias[n0 + tx * 8 + j];
            if (relu) v = fmaxf(v, 0.f);
            crow[tx * 8 + j] = v;
        }
    }
}

// ---------------------------------------------------------------------------
// LayerNorm over D=768 per row. One block (256 threads) per row. x==y OK.
// var = E[x^2] - mu^2 (matches jnp.var, biased), eps=1e-5.
// ---------------------------------------------------------------------------
__global__ __launch_bounds__(256) void ln_kernel(
    const float* __restrict__ x, float* __restrict__ y,
    const float* __restrict__ g, const float* __restrict__ b)
{
    const int n = blockIdx.x;
    const float* xr = x + (size_t)n * DIM;
    float v[3];
    float s = 0.f, s2 = 0.f;
#pragma unroll
    for (int i = 0; i < 3; ++i) {
        v[i] = xr[threadIdx.x + i * 256];
        s += v[i];
        s2 += v[i] * v[i];
    }
#pragma unroll
    for (int sft = 32; sft > 0; sft >>= 1) {
        s += __shfl_down(s, sft);
        s2 += __shfl_down(s2, sft);
    }
    __shared__ float ls[4], ls2[4];
    const int w = threadIdx.x >> 6;
    if ((threadIdx.x & 63) == 0) { ls[w] = s; ls2[w] = s2; }
    __syncthreads();
    s  = ls[0] + ls[1] + ls[2] + ls[3];
    s2 = ls2[0] + ls2[1] + ls2[2] + ls2[3];
    const float mu = s * (1.f / DIM);
    const float var = s2 * (1.f / DIM) - mu * mu;
    const float r = rsqrtf(var + 1e-5f);
    float* yr = y + (size_t)n * DIM;
#pragma unroll
    for (int i = 0; i < 3; ++i) {
        int d = threadIdx.x + i * 256;
        yr[d] = (v[i] - mu) * r * g[d] + b[d];
    }
}

// ---------------------------------------------------------------------------
// Gating: one wave per token. logits = z @ wg ([D,E]); top-2 (first-occurrence
// tie-break like lax.top_k) + softmax over the 2; atomic per-expert position.
// ---------------------------------------------------------------------------
__global__ __launch_bounds__(64) void gate_kernel(
    const float* __restrict__ z, const float* __restrict__ wg,
    float* __restrict__ gw, int* __restrict__ gidx, int* __restrict__ gpos,
    int* __restrict__ counts)
{
    const int n = blockIdx.x;
    const int lane = threadIdx.x;
    const float* zr = z + (size_t)n * DIM;
    float acc[NEXP];
#pragma unroll
    for (int e = 0; e < NEXP; ++e) acc[e] = 0.f;
    for (int d = lane; d < DIM; d += 64) {
        float zv = zr[d];
        const float* wr = wg + (size_t)d * NEXP;
#pragma unroll
        for (int e = 0; e < NEXP; ++e) acc[e] += zv * wr[e];
    }
#pragma unroll
    for (int e = 0; e < NEXP; ++e)
#pragma unroll
        for (int sft = 32; sft > 0; sft >>= 1) acc[e] += __shfl_down(acc[e], sft);

    if (lane == 0) {
        int i0 = 0;
        for (int e = 1; e < NEXP; ++e)
            if (acc[e] > acc[i0]) i0 = e;
        int i1 = -1;
        for (int e = 0; e < NEXP; ++e) {
            if (e == i0) continue;
            if (i1 < 0 || acc[e] > acc[i1]) i1 = e;
        }
        float v0 = acc[i0], v1 = acc[i1];
        float e1 = __expf(v1 - v0);         // v0 is the max
        float inv = 1.f / (1.f + e1);
        gw[n * 2 + 0] = inv;
        gw[n * 2 + 1] = e1 * inv;
        gidx[n * 2 + 0] = i0;
        gidx[n * 2 + 1] = i1;
        gpos[n * 2 + 0] = atomicAdd(&counts[i0], 1);
        gpos[n * 2 + 1] = atomicAdd(&counts[i1], 1);
    }
}

__global__ void zero_counts(int* counts)
{
    if (threadIdx.x < NEXP) counts[threadIdx.x] = 0;
}

__global__ void scan_counts(const int* __restrict__ counts, int* __restrict__ offs)
{
    if (threadIdx.x == 0) {
        int o = 0;
        for (int e = 0; e < NEXP; ++e) { offs[e] = o; o += counts[e]; }
    }
}

__global__ __launch_bounds__(256) void build_kernel(
    const int* __restrict__ gidx, const int* __restrict__ gpos,
    const int* __restrict__ offs, int* __restrict__ lst,
    int* __restrict__ pairslot)
{
    const int n = blockIdx.x * blockDim.x + threadIdx.x;
    if (n >= NTOK) return;
#pragma unroll
    for (int k = 0; k < TOPK; ++k) {
        int e = gidx[n * 2 + k];
        int p = gpos[n * 2 + k];
        int slot = offs[e] + p;
        pairslot[n * 2 + k] = slot;
        lst[e * NTOK + p] = n;
    }
}

// h[n] += w0*y[slot0] + w1*y[slot1]   (residual + gate-weighted combine)
__global__ __launch_bounds__(256) void combine_kernel(
    float* __restrict__ h, const float* __restrict__ ybuf,
    const float* __restrict__ gw, const int* __restrict__ pairslot)
{
    const int n = blockIdx.x;
    const float w0 = gw[n * 2 + 0], w1 = gw[n * 2 + 1];
    const int s0 = pairslot[n * 2 + 0], s1 = pairslot[n * 2 + 1];
    const float* y0 = ybuf + (size_t)s0 * DIM;
    const float* y1 = ybuf + (size_t)s1 * DIM;
    float* hr = h + (size_t)n * DIM;
    for (int d = threadIdx.x; d < DIM; d += 256)
        hr[d] += w0 * y0[d] + w1 * y1[d];
}

// ---------------------------------------------------------------------------
extern "C" void kernel_launch(void* const* d_in, const int* in_sizes, int n_in,
                              void* d_out, int out_size, void* d_ws, size_t ws_size,
                              hipStream_t stream)
{
    const float* x        = (const float*)d_in[0];
    const float* w_in     = (const float*)d_in[1];
    const float* b_in     = (const float*)d_in[2];
    const float* g_in     = (const float*)d_in[3];
    const float* beta_in  = (const float*)d_in[4];
    const float* g_ln     = (const float*)d_in[5];
    const float* beta_ln  = (const float*)d_in[6];
    const float* w_gate   = (const float*)d_in[7];
    const float* w1       = (const float*)d_in[8];
    const float* b1       = (const float*)d_in[9];
    const float* w2       = (const float*)d_in[10];
    const float* b2       = (const float*)d_in[11];
    const float* w_out    = (const float*)d_in[12];
    const float* b_out    = (const float*)d_in[13];
    const float* g_out    = (const float*)d_in[14];
    const float* beta_out = (const float*)d_in[15];
    float* out = (float*)d_out;

    // Workspace carve-up (~76 MB)
    float* h    = (float*)d_ws;                       // [NTOK, DIM]
    float* z    = h    + (size_t)NTOK * DIM;          // [NTOK, DIM]
    float* h1   = z    + (size_t)NTOK * DIM;          // [NTOK*K, FDIM]
    float* ybuf = h1   + (size_t)NTOK * TOPK * FDIM;  // [NTOK*K, DIM]
    float* gw   = ybuf + (size_t)NTOK * TOPK * DIM;   // [NTOK, K]
    int* gidx     = (int*)(gw + NTOK * TOPK);         // [NTOK, K]
    int* gpos     = gidx + NTOK * TOPK;               // [NTOK, K]
    int* counts   = gpos + NTOK * TOPK;               // [E]
    int* offs     = counts + NEXP;                    // [E]
    int* lst      = offs + NEXP;                      // [E, NTOK]
    int* pairslot = lst + NEXP * NTOK;                // [NTOK, K]

    const dim3 blk(256);

    // in_proj + input LN (in-place)
    gemm_f32<<<dim3(DIM / 128, NTOK / 128), blk, 0, stream>>>(
        x, w_in, b_in, h, NTOK, DIM, DIM);
    ln_kernel<<<NTOK, 256, 0, stream>>>(h, h, g_in, beta_in);

    for (int l = 0; l < NLAYER; ++l) {
        zero_counts<<<1, 64, 0, stream>>>(counts);
        ln_kernel<<<NTOK, 256, 0, stream>>>(h, z, g_ln + (size_t)l * DIM,
                                            beta_ln + (size_t)l * DIM);
        gate_kernel<<<NTOK, 64, 0, stream>>>(
            z, w_gate + (size_t)l * DIM * NEXP, gw, gidx, gpos, counts);
        scan_counts<<<1, 1, 0, stream>>>(counts, offs);
        build_kernel<<<NTOK / 256, 256, 0, stream>>>(gidx, gpos, offs, lst, pairslot);

        // h1[slot] = relu(z[tok] @ w1[l,e] + b1[l,e])   (gathered rows)
        gemm_grouped<<<dim3(FDIM / 128, NTOK / 128, NEXP), blk, 0, stream>>>(
            z, w1 + (size_t)l * NEXP * DIM * FDIM, b1 + (size_t)l * NEXP * FDIM,
            h1, counts, offs, lst, DIM, FDIM, (size_t)DIM * FDIM, FDIM, 1);

        // y[slot] = h1[slot] @ w2[l,e] + b2[l,e]
        gemm_grouped<<<dim3(DIM / 128, NTOK / 128, NEXP), blk, 0, stream>>>(
            h1, w2 + (size_t)l * NEXP * FDIM * DIM, b2 + (size_t)l * NEXP * DIM,
            ybuf, counts, offs, nullptr, FDIM, DIM, (size_t)FDIM * DIM, DIM, 0);

        combine_kernel<<<NTOK, 256, 0, stream>>>(h, ybuf, gw, pairslot);
    }

    // out_proj + final LN (into d_out)
    gemm_f32<<<dim3(DIM / 128, NTOK / 128), blk, 0, stream>>>(
        h, w_out, b_out, z, NTOK, DIM, DIM);
    ln_kernel<<<NTOK, 256, 0, stream>>>(z, out, g_out, beta_out);
}